// Round 3
// baseline (9744.014 us; speedup 1.0000x reference)
//
#include <hip/hip_runtime.h>
#include <math.h>

// ---------------------------------------------------------------------------
// WorldModel RSSM forward losses — R8.
// R7 (cooperative grid.sync) regressed 3044->9597us: grid.sync costs ~67us
// at 256 blocks (MfmaUtil 0.77%!). The fused decomposition itself was proven
// correct (absmax 0.0). R8 keeps the fusion but replaces grid.sync with
// per-stripe producer/consumer flag counters:
//  * one NORMAL launch per group (9 total for phase B, was 126 kernels).
//  * 256 blocks = 4 batch-stripes x 64 n-tiles; co-resident by capacity.
//  * stage-1 (all blocks): G/latent GEMM; latent blocks fuse z/KL epilogue.
//    producers bump flagA[m] (target 64/step).
//  * stage-2 (n<16 blocks): 64x64 GRU gate GEMM + state update; bump
//    flagB[m] (target 16/step). Stripes pipeline independently.
//  * flags monotonic across steps+groups, zeroed each graph replay by the
//    phase-0 zero kernel.
//  * sync cost/block/step: 1 threadfence (wbl2) + 1 device atomicAdd +
//    1 acquire-spin — no global barrier anywhere.
// ---------------------------------------------------------------------------

namespace {

typedef unsigned short ushort;
typedef __attribute__((ext_vector_type(8))) short short8;   // 8 bf16 in 4 VGPRs
typedef __attribute__((ext_vector_type(4))) float f32x4;

constexpr int TSTEPS = 63;
constexpr int NB     = 256;
constexpr int NACT   = 32;
constexpr int NROWS  = TSTEPS * NB;   // 16128
constexpr int TGRP   = 7;
constexpr int NGRP   = 9;
constexpr int GROWS  = TGRP * NB;     // 1792 = 28*64

// ---- workspace layout (floats) --------------------------------------------
constexpr size_t OFF_POSTE = 0;                                     // f32 16128x512
constexpr size_t OFF_OBSB  = OFF_POSTE + (size_t)NROWS * 512;       // (unused)
constexpr size_t OFF_E1C   = OFF_OBSB + (size_t)GROWS * 512 / 2;    // u16 1792x1024
constexpr size_t OFF_EMBC  = OFF_E1C + (size_t)GROWS * 1024 / 2;    // u16 1792x1024
constexpr size_t OFF_FEATC = OFF_EMBC + (size_t)GROWS * 1024 / 2;   // u16 1792x1280
constexpr size_t OFF_DR1C  = OFF_FEATC + (size_t)GROWS * 1280 / 2;  // u16 1792x2048
constexpr size_t OFF_WHT   = OFF_DR1C + (size_t)GROWS * 2048 / 2;   // u16 4096x1024
constexpr size_t OFF_WIHT  = OFF_WHT + (size_t)4096 * 1024 / 2;     // u16 3072x288
constexpr size_t OFF_WDRT  = OFF_WIHT + (size_t)3072 * 288 / 2;     // u16 2048x1280
constexpr size_t OFF_E1T   = OFF_WDRT + (size_t)2048 * 1280 / 2;    // u16 1024x512
constexpr size_t OFF_E2T   = OFF_E1T + (size_t)1024 * 512 / 2;      // u16 1024x1024
constexpr size_t OFF_PET   = OFF_E2T + (size_t)1024 * 1024 / 2;     // u16 512x1024
constexpr size_t OFF_DW2T  = OFF_PET + (size_t)512 * 1024 / 2;      // u16 512x1024
constexpr size_t OFF_BDR   = OFF_DW2T + (size_t)512 * 1024 / 2;     // f32 2048
constexpr size_t OFF_G     = OFF_BDR + 2048;                        // f32 256x3072
constexpr size_t OFF_H     = OFF_G + (size_t)NB * 3072;             // f32 256x1024
constexpr size_t OFF_HB    = OFF_H + (size_t)NB * 1024;             // u16 256x1024
constexpr size_t OFF_ACC   = OFF_HB + (size_t)NB * 1024 / 2;        // f32 16
constexpr size_t OFF_XBUF  = OFF_ACC + 16;                          // u16 256x288
constexpr size_t OFF_FLAGS = OFF_XBUF + (size_t)NB * 288 / 2;       // i32 16

__device__ __forceinline__ ushort f2bf(float f) {
  unsigned int u = __float_as_uint(f);
  unsigned int r = (u + 0x7fffu + ((u >> 16) & 1u)) >> 16;
  return (ushort)r;
}
__device__ __forceinline__ float bf2f(ushort u) {
  return __uint_as_float((unsigned int)u << 16);
}

__global__ void zero_kernel(float* p, int n) {
  int i = blockIdx.x * 256 + threadIdx.x;
  if (i < n) p[i] = 0.f;
}

__global__ void f2bf_kernel(const float* __restrict__ in, ushort* __restrict__ out, int n) {
  int i = blockIdx.x * 256 + threadIdx.x;
  if (i < n) out[i] = f2bf(in[i]);
}

// WHT[n][k]. n<1024: latent-permuted — quad q=(n>>4)&3 selects pm/pl/qm/ql,
// s = (n>>6)*16 + (n&15). n>=1024: whh[n-1024][k] (gh part).
__global__ void build_wht(const float* __restrict__ prior_w, const float* __restrict__ post_w,
                          const float* __restrict__ whh, ushort* __restrict__ out) {
  int idx = blockIdx.x * 256 + threadIdx.x;  // 4096*1024
  int n = idx >> 10, k = idx & 1023;
  float v;
  if (n < 1024) {
    int q = (n >> 4) & 3;
    int s = ((n >> 6) << 4) | (n & 15);
    v = (q == 0) ? prior_w[k * 512 + s]
      : (q == 1) ? prior_w[k * 512 + 256 + s]
      : (q == 2) ? post_w[k * 512 + s]
                 : post_w[k * 512 + 256 + s];
  } else {
    v = whh[(size_t)(n - 1024) * 1024 + k];
  }
  out[idx] = f2bf(v);
}

// out[c*ldo + r] = bf16(in[r*ldi + c]); grid (C/32, R/32)
__global__ void trans_conv(const float* __restrict__ in, ushort* __restrict__ out,
                           int ldi, int ldo) {
  __shared__ float tile[32][33];
  int r0 = blockIdx.y * 32, c0 = blockIdx.x * 32;
  int tx = threadIdx.x & 31, ty = threadIdx.x >> 5;
#pragma unroll
  for (int p = 0; p < 4; ++p)
    tile[ty + p * 8][tx] = in[(size_t)(r0 + ty + p * 8) * ldi + c0 + tx];
  __syncthreads();
#pragma unroll
  for (int p = 0; p < 4; ++p)
    out[(size_t)(c0 + ty + p * 8) * ldo + r0 + tx] = f2bf(tile[tx][ty + p * 8]);
}

__global__ void build_bdr(const float* __restrict__ dec_b1, const float* __restrict__ rew_b1,
                          float* __restrict__ bdr) {
  int i = blockIdx.x * 256 + threadIdx.x;  // 2048
  bdr[i] = (i < 1024) ? dec_b1[i] : rew_b1[i - 1024];
}

// ---------------------------------------------------------------------------
// Phase A/C bf16 GEMM (R6 body, proven): 64x64 tile, 4 waves, BK=32, LDS
// stride 40, register prefetch + LDS double buffer (one barrier/iter).
// EPI: 1 = +bias, relu, store bf16; 2 = +bias, store f32.
// ---------------------------------------------------------------------------
template <int EPI, bool AF32>
__global__ __launch_bounds__(256) void gemm_bf16(
    const void* __restrict__ Av, const ushort* __restrict__ BT,
    const float* __restrict__ bias, void* __restrict__ Cv,
    int K, int lda, int ldb, int ldc) {
  __shared__ __align__(16) ushort As[2][64 * 40];
  __shared__ __align__(16) ushort Bs[2][64 * 40];
  int tid = threadIdx.x;
  int wave = tid >> 6, lane = tid & 63;
  int quad = lane >> 4, l15 = lane & 15;
  int m0 = blockIdx.y * 64, n0 = blockIdx.x * 64;
  int sr = tid >> 2, sc = (tid & 3) * 8;
  const ushort* agb = (const ushort*)Av + (size_t)(m0 + sr) * lda + sc;
  const float*  agf = (const float*)Av + (size_t)(m0 + sr) * lda + sc;
  const ushort* bgp = BT + (size_t)(n0 + sr) * ldb + sc;
  int4 pa0, pa1, pb;
  if (AF32) { pa0 = *(const int4*)agf; pa1 = *(const int4*)(agf + 4); }
  else      { pa0 = *(const int4*)agb; }
  pb = *(const int4*)bgp;
  f32x4 acc[4] = {};
  int buf = 0;
  for (int k0 = 0; k0 < K; k0 += 32, buf ^= 1) {
    int4 st;
    if (AF32) {
      float f[8];
      *(int4*)&f[0] = pa0; *(int4*)&f[4] = pa1;
      ushort u[8];
#pragma unroll
      for (int i = 0; i < 8; ++i) u[i] = f2bf(f[i]);
      st = *(const int4*)u;
    } else {
      st = pa0;
    }
    *(int4*)&As[buf][sr * 40 + sc] = st;
    *(int4*)&Bs[buf][sr * 40 + sc] = pb;
    __syncthreads();
    int kn = k0 + 32;
    if (kn < K) {
      if (AF32) { pa0 = *(const int4*)(agf + kn); pa1 = *(const int4*)(agf + kn + 4); }
      else      { pa0 = *(const int4*)(agb + kn); }
      pb = *(const int4*)(bgp + kn);
    }
    short8 a = *(const short8*)&As[buf][(wave * 16 + l15) * 40 + quad * 8];
#pragma unroll
    for (int c = 0; c < 4; ++c) {
      short8 b = *(const short8*)&Bs[buf][(c * 16 + l15) * 40 + quad * 8];
      acc[c] = __builtin_amdgcn_mfma_f32_16x16x32_bf16(a, b, acc[c], 0, 0, 0);
    }
  }
#pragma unroll
  for (int c = 0; c < 4; ++c) {
#pragma unroll
    for (int r = 0; r < 4; ++r) {
      size_t row = m0 + wave * 16 + quad * 4 + r;
      int col = n0 + c * 16 + l15;
      float v = acc[c][r] + bias[col];
      if (EPI == 1) v = fmaxf(v, 0.f);
      if (EPI == 1) ((ushort*)Cv)[row * ldc + col] = f2bf(v);
      else ((float*)Cv)[row * ldc + col] = v;
    }
  }
}

// ---------------------------------------------------------------------------
// R8 Phase B: one NORMAL launch per group; flag-based per-stripe dataflow.
// grid = 256 blocks x 256 threads. bid = m*64 + n (m: 4 batch stripes of 64
// rows, n: 64 n-tiles of WHT's 4096 cols).
// Step t:
//   [wait flagB[m] >= 16*t]  (HB of step t ready)
//   stage 1: 64x64 tile of HB @ WHT, K=1024, BK=64 dbuf.
//            n<16 -> latent epilogue (z into xbuf/featc, KL atomic).
//            n>=16 -> gh tile into G.
//   [bump flagA[m]; latent blocks wait flagA[m] >= 64*(t+1)]
//   stage 2 (n<16): gi = xbuf @ wihT (3 gates, 64 rows x 64 cols, K=288)
//            + GRU gate epilogue -> H, HB, featc. [bump flagB[m]]
// Flags monotonic across steps and groups; zeroed once per graph replay.
// ---------------------------------------------------------------------------
__global__ __launch_bounds__(256) void phaseb_group_kernel(
    int g0,
    ushort* __restrict__ HB, const ushort* __restrict__ WHT,
    const float* __restrict__ prior_b, const float* __restrict__ poste,
    const float* __restrict__ eps, const float* __restrict__ actions,
    const unsigned char* __restrict__ dones,
    const ushort* __restrict__ wiht, const float* __restrict__ bih,
    const float* __restrict__ bhh,
    float* __restrict__ G, ushort* __restrict__ xbuf,
    float* __restrict__ H, ushort* __restrict__ featc,
    float* __restrict__ acc_kl, int* __restrict__ flags) {
  __shared__ __align__(16) char smem[40960];
  ushort* As1 = (ushort*)smem;              // [2][64*72]
  ushort* Bs1 = (ushort*)(smem + 18432);    // [2][64*72]
  ushort* As2 = (ushort*)smem;              // [2][64*40]
  ushort* Bs2 = (ushort*)(smem + 10240);    // [2][3][64*40]
  int* flagA = flags;       // counts stage-1 blocks per stripe (64/step)
  int* flagB = flags + 4;   // counts stage-2 blocks per stripe (16/step)

  int tid = threadIdx.x;
  int wave = tid >> 6, lane = tid & 63;
  int quad = lane >> 4, l15 = lane & 15;
  int bid = blockIdx.x;
  int n1 = bid & 63, m = bid >> 6;
  int m0 = m * 64, n01 = n1 * 64;

  // stage-1 staging addresses
  int sr1 = tid >> 2, sc1 = (tid & 3) * 16;
  const ushort* agp1 = HB + (size_t)(m0 + sr1) * 1024 + sc1;
  const ushort* bgp1 = WHT + (size_t)(n01 + sr1) * 1024 + sc1;
  // stage-2 staging addresses (only used when n1 < 16)
  int sr2 = tid >> 2, sc2 = (tid & 3) * 8;
  const ushort* agp2 = xbuf + (size_t)(m0 + sr2) * 288 + sc2;
  const ushort* bgp2 = wiht + (size_t)(n01 + sr2) * 288 + sc2;

  for (int tt = 0; tt < TGRP; ++tt) {
    int t = g0 + tt;
    // ---- wait: HB for step t is complete (stage-2 of step t-1) ----------
    if (tid == 0) {
      while (__hip_atomic_load(&flagB[m], __ATOMIC_ACQUIRE, __HIP_MEMORY_SCOPE_AGENT) < 16 * t)
        __builtin_amdgcn_s_sleep(1);
    }
    __syncthreads();
    // ---------------- stage 1: HB @ WHT -----------------------------------
    {
      int4 a0 = *(const int4*)agp1, a1 = *(const int4*)(agp1 + 8);
      int4 b0 = *(const int4*)bgp1, b1 = *(const int4*)(bgp1 + 8);
      f32x4 acc[4] = {};
      int buf = 0;
      for (int k0 = 0; k0 < 1024; k0 += 64, buf ^= 1) {
        ushort* as = As1 + buf * 4608;
        ushort* bs = Bs1 + buf * 4608;
        *(int4*)&as[sr1 * 72 + sc1] = a0; *(int4*)&as[sr1 * 72 + sc1 + 8] = a1;
        *(int4*)&bs[sr1 * 72 + sc1] = b0; *(int4*)&bs[sr1 * 72 + sc1 + 8] = b1;
        __syncthreads();
        int kn = k0 + 64;
        if (kn < 1024) {
          a0 = *(const int4*)(agp1 + kn); a1 = *(const int4*)(agp1 + kn + 8);
          b0 = *(const int4*)(bgp1 + kn); b1 = *(const int4*)(bgp1 + kn + 8);
        }
#pragma unroll
        for (int kk = 0; kk < 2; ++kk) {
          short8 a = *(const short8*)&as[(wave * 16 + l15) * 72 + kk * 32 + quad * 8];
#pragma unroll
          for (int c = 0; c < 4; ++c) {
            short8 b = *(const short8*)&bs[(c * 16 + l15) * 72 + kk * 32 + quad * 8];
            acc[c] = __builtin_amdgcn_mfma_f32_16x16x32_bf16(a, b, acc[c], 0, 0, 0);
          }
        }
      }
      if (n1 < 16) {
        // latent epilogue: acc[0..3] = pm,pl,qm,ql for s = n1*16 + l15
        int s = (n01 >> 2) + l15;
        float kl_sum = 0.f;
#pragma unroll
        for (int r = 0; r < 4; ++r) {
          int b = m0 + wave * 16 + quad * 4 + r;
          size_t row = (size_t)t * NB + b;
          float pm = acc[0][r] + prior_b[s];
          float pl = acc[1][r] + prior_b[256 + s];
          float qm = acc[2][r] + poste[row * 512 + s];
          float ql = acc[3][r] + poste[row * 512 + 256 + s];
          float e = eps[row * 256 + s];
          float z = qm + e * expf(ql);
          xbuf[b * 288 + s] = f2bf(z);
          featc[(size_t)(tt * NB + b) * 1280 + 1024 + s] = f2bf(z);
          if (s < NACT) xbuf[b * 288 + 256 + s] = f2bf(actions[row * NACT + s]);
          float vq = expf(2.f * ql), vp = expf(2.f * pl);
          float dm = qm - pm;
          kl_sum += pl - ql + (vq + dm * dm) / (vp + 1e-8f) - 1.f;
        }
        for (int off = 32; off > 0; off >>= 1) kl_sum += __shfl_down(kl_sum, off);
        if (lane == 0) atomicAdd(acc_kl, 0.5f * kl_sum);
      } else {
        int ng = n01 - 1024;
#pragma unroll
        for (int c = 0; c < 4; ++c)
#pragma unroll
          for (int r = 0; r < 4; ++r) {
            int b = m0 + wave * 16 + quad * 4 + r;
            G[(size_t)b * 3072 + ng + c * 16 + l15] = acc[c][r];
          }
      }
    }
    __syncthreads();
    if (tid == 0) {
      __threadfence();  // make this block's xbuf/G/featc stores agent-visible
      __hip_atomic_fetch_add(&flagA[m], 1, __ATOMIC_RELAXED, __HIP_MEMORY_SCOPE_AGENT);
    }
    // ---------------- stage 2 (latent blocks): GRU ------------------------
    if (n1 < 16) {
      if (tid == 0) {
        while (__hip_atomic_load(&flagA[m], __ATOMIC_ACQUIRE, __HIP_MEMORY_SCOPE_AGENT) < 64 * (t + 1))
          __builtin_amdgcn_s_sleep(1);
      }
      __syncthreads();
      int4 pa = *(const int4*)agp2;
      int4 pb0 = *(const int4*)bgp2;
      int4 pb1 = *(const int4*)(bgp2 + (size_t)1024 * 288);
      int4 pb2 = *(const int4*)(bgp2 + (size_t)2048 * 288);
      f32x4 accv[3][4] = {};
      int buf = 0;
      for (int k0 = 0; k0 < 288; k0 += 32, buf ^= 1) {
        ushort* as = As2 + buf * 2560;
        ushort* bs = Bs2 + buf * 7680;
        *(int4*)&as[sr2 * 40 + sc2] = pa;
        *(int4*)&bs[sr2 * 40 + sc2] = pb0;
        *(int4*)&bs[2560 + sr2 * 40 + sc2] = pb1;
        *(int4*)&bs[5120 + sr2 * 40 + sc2] = pb2;
        __syncthreads();
        int kn = k0 + 32;
        if (kn < 288) {
          pa = *(const int4*)(agp2 + kn);
          pb0 = *(const int4*)(bgp2 + kn);
          pb1 = *(const int4*)(bgp2 + (size_t)1024 * 288 + kn);
          pb2 = *(const int4*)(bgp2 + (size_t)2048 * 288 + kn);
        }
        short8 a = *(const short8*)&as[(wave * 16 + l15) * 40 + quad * 8];
#pragma unroll
        for (int gg = 0; gg < 3; ++gg) {
#pragma unroll
          for (int c = 0; c < 4; ++c) {
            short8 b = *(const short8*)&bs[gg * 2560 + (c * 16 + l15) * 40 + quad * 8];
            accv[gg][c] = __builtin_amdgcn_mfma_f32_16x16x32_bf16(a, b, accv[gg][c], 0, 0, 0);
          }
        }
      }
#pragma unroll
      for (int c = 0; c < 4; ++c) {
#pragma unroll
        for (int r = 0; r < 4; ++r) {
          int b_idx = m0 + wave * 16 + quad * 4 + r;
          int j = n01 + c * 16 + l15;
          const float* g = G + (size_t)b_idx * 3072;
          float ir = accv[0][c][r] + bih[j];
          float iz = accv[1][c][r] + bih[1024 + j];
          float in_ = accv[2][c][r] + bih[2048 + j];
          float hr = g[j] + bhh[j];
          float hz = g[1024 + j] + bhh[1024 + j];
          float hn = g[2048 + j] + bhh[2048 + j];
          float rg = 1.f / (1.f + expf(-(ir + hr)));
          float u = 1.f / (1.f + expf(-(iz + hz)));
          float n = tanhf(in_ + rg * hn);
          float hprev = H[b_idx * 1024 + j];
          float hnext = (1.f - u) * n + u * hprev;
          featc[(size_t)(tt * NB + b_idx) * 1280 + j] = f2bf(hnext);
          float mask = 1.f - (float)dones[t * NB + b_idx];
          float hm = hnext * mask;
          H[b_idx * 1024 + j] = hm;
          HB[b_idx * 1024 + j] = f2bf(hm);
        }
      }
      __syncthreads();
      if (tid == 0) {
        __threadfence();  // make H/HB stores agent-visible
        __hip_atomic_fetch_add(&flagB[m], 1, __ATOMIC_RELAXED, __HIP_MEMORY_SCOPE_AGENT);
      }
    }
  }
}

// ---------------------------------------------------------------------------
// Decoder-out GEMM + fused recon loss (R6 body).
// ---------------------------------------------------------------------------
__global__ __launch_bounds__(256) void decobs_loss_kernel(
    const ushort* __restrict__ A, const ushort* __restrict__ BT,
    const float* __restrict__ bias, const float* __restrict__ obs_next_g,
    float* __restrict__ acc) {
  __shared__ __align__(16) ushort As[2][64 * 40];
  __shared__ __align__(16) ushort Bs[2][64 * 40];
  int tid = threadIdx.x;
  int wave = tid >> 6, lane = tid & 63;
  int quad = lane >> 4, l15 = lane & 15;
  int m0 = blockIdx.y * 64, n0 = blockIdx.x * 64;
  int sr = tid >> 2, sc = (tid & 3) * 8;
  const ushort* agp = A + (size_t)(m0 + sr) * 2048 + sc;
  const ushort* bgp = BT + (size_t)(n0 + sr) * 1024 + sc;
  int4 pa = *(const int4*)agp;
  int4 pb = *(const int4*)bgp;
  f32x4 accm[4] = {};
  int buf = 0;
  for (int k0 = 0; k0 < 1024; k0 += 32, buf ^= 1) {
    *(int4*)&As[buf][sr * 40 + sc] = pa;
    *(int4*)&Bs[buf][sr * 40 + sc] = pb;
    __syncthreads();
    int kn = k0 + 32;
    if (kn < 1024) {
      pa = *(const int4*)(agp + kn);
      pb = *(const int4*)(bgp + kn);
    }
    short8 a = *(const short8*)&As[buf][(wave * 16 + l15) * 40 + quad * 8];
#pragma unroll
    for (int c = 0; c < 4; ++c) {
      short8 b = *(const short8*)&Bs[buf][(c * 16 + l15) * 40 + quad * 8];
      accm[c] = __builtin_amdgcn_mfma_f32_16x16x32_bf16(a, b, accm[c], 0, 0, 0);
    }
  }
  float local = 0.f;
#pragma unroll
  for (int c = 0; c < 4; ++c) {
#pragma unroll
    for (int r = 0; r < 4; ++r) {
      size_t row = m0 + wave * 16 + quad * 4 + r;
      int col = n0 + c * 16 + l15;
      float v = accm[c][r] + bias[col];
      float d = v - obs_next_g[row * 512 + col];
      local += d * d;
    }
  }
  __shared__ float red[256];
  red[tid] = local;
  __syncthreads();
  for (int st = 128; st > 0; st >>= 1) {
    if (tid < st) red[tid] += red[tid + st];
    __syncthreads();
  }
  if (tid == 0) atomicAdd(&acc[0], red[0]);
}

// Reward matvec + loss. R1 = DR1C + 1024 (bf16, row stride 2048).
__global__ __launch_bounds__(256) void rew_loss_kernel(
    const ushort* __restrict__ R1, const float* __restrict__ w2,
    const float* __restrict__ b2, const float* __restrict__ rewards_g,
    float* __restrict__ acc) {
  int wave = threadIdx.x >> 6;
  int lane = threadIdx.x & 63;
  int row = blockIdx.x * 4 + wave;
  const ushort* rp = R1 + (size_t)row * 2048;
  float s = 0.f;
#pragma unroll
  for (int i = 0; i < 16; ++i) s += bf2f(rp[lane + 64 * i]) * w2[lane + 64 * i];
  for (int off = 32; off > 0; off >>= 1) s += __shfl_down(s, off);
  if (lane == 0) {
    float d = s + b2[0] - rewards_g[row];
    atomicAdd(&acc[1], d * d);
  }
}

__global__ void finalize_kernel(const float* __restrict__ acc, float* __restrict__ out) {
  float recon = acc[0] / ((float)NROWS * 512.f);
  float rew = acc[1] / (float)NROWS;
  float kl = acc[2] / (float)NROWS;
  out[0] = recon + rew + kl;
  out[1] = recon;
  out[2] = rew;
  out[3] = kl;
}

}  // namespace

extern "C" void kernel_launch(void* const* d_in, const int* in_sizes, int n_in,
                              void* d_out, int out_size, void* d_ws, size_t ws_size,
                              hipStream_t stream) {
  const float* obs     = (const float*)d_in[0];
  const float* actions = (const float*)d_in[1];
  const float* rewards = (const float*)d_in[2];
  const unsigned char* dones = (const unsigned char*)d_in[3];
  const float* eps     = (const float*)d_in[4];
  const float* enc_w1  = (const float*)d_in[5];
  const float* enc_b1  = (const float*)d_in[6];
  const float* enc_w2  = (const float*)d_in[7];
  const float* enc_b2  = (const float*)d_in[8];
  const float* gru_wih = (const float*)d_in[9];
  const float* gru_whh = (const float*)d_in[10];
  const float* gru_bih = (const float*)d_in[11];
  const float* gru_bhh = (const float*)d_in[12];
  const float* prior_w = (const float*)d_in[13];
  const float* prior_b = (const float*)d_in[14];
  const float* post_w  = (const float*)d_in[15];
  const float* post_b  = (const float*)d_in[16];
  const float* dec_w1  = (const float*)d_in[17];
  const float* dec_b1  = (const float*)d_in[18];
  const float* dec_w2  = (const float*)d_in[19];
  const float* dec_b2  = (const float*)d_in[20];
  const float* rew_w1  = (const float*)d_in[21];
  const float* rew_b1  = (const float*)d_in[22];
  const float* rew_w2  = (const float*)d_in[23];
  const float* rew_b2  = (const float*)d_in[24];
  float* out = (float*)d_out;
  float* ws = (float*)d_ws;

  float*  POSTE = ws + OFF_POSTE;
  ushort* E1C   = (ushort*)(ws + OFF_E1C);
  ushort* EMBC  = (ushort*)(ws + OFF_EMBC);
  ushort* FEATC = (ushort*)(ws + OFF_FEATC);
  ushort* DR1C  = (ushort*)(ws + OFF_DR1C);
  ushort* WHT   = (ushort*)(ws + OFF_WHT);
  ushort* WIHT  = (ushort*)(ws + OFF_WIHT);
  ushort* WDRT  = (ushort*)(ws + OFF_WDRT);
  ushort* E1T   = (ushort*)(ws + OFF_E1T);
  ushort* E2T   = (ushort*)(ws + OFF_E2T);
  ushort* PET   = (ushort*)(ws + OFF_PET);
  ushort* DW2T  = (ushort*)(ws + OFF_DW2T);
  float*  BDR   = ws + OFF_BDR;
  float*  G     = ws + OFF_G;
  float*  H     = ws + OFF_H;
  ushort* HB    = (ushort*)(ws + OFF_HB);
  float*  ACC   = ws + OFF_ACC;
  ushort* XBUF  = (ushort*)(ws + OFF_XBUF);
  int*    FLAGS = (int*)(ws + OFF_FLAGS);

  // Phase 0: zero H + HB + ACC + XBUF + FLAGS (contiguous), build bf16 weights
  {
    int nzero = NB * 1024 + NB * 512 + 16 + NB * 288 / 2 + 16;
    zero_kernel<<<(nzero + 255) / 256, 256, 0, stream>>>(H, nzero);
  }
  build_wht<<<4096 * 1024 / 256, 256, 0, stream>>>(prior_w, post_w, gru_whh, WHT);
  f2bf_kernel<<<(3072 * 288) / 256, 256, 0, stream>>>(gru_wih, WIHT, 3072 * 288);
  trans_conv<<<dim3(1024 / 32, 1280 / 32), 256, 0, stream>>>(dec_w1, WDRT, 1024, 1280);
  trans_conv<<<dim3(1024 / 32, 1280 / 32), 256, 0, stream>>>(rew_w1, WDRT + (size_t)1024 * 1280, 1024, 1280);
  trans_conv<<<dim3(1024 / 32, 512 / 32), 256, 0, stream>>>(enc_w1, E1T, 1024, 512);
  trans_conv<<<dim3(1024 / 32, 1024 / 32), 256, 0, stream>>>(enc_w2, E2T, 1024, 1024);
  trans_conv<<<dim3(512 / 32, 1024 / 32), 256, 0, stream>>>(post_w + (size_t)1024 * 512, PET, 512, 1024);
  trans_conv<<<dim3(512 / 32, 1024 / 32), 256, 0, stream>>>(dec_w2, DW2T, 512, 1024);
  build_bdr<<<8, 256, 0, stream>>>(dec_b1, rew_b1, BDR);

  // Phase A: encoder + posterior-from-emb, chunked per group.
  for (int g = 0; g < NGRP; ++g) {
    const float* obs_g = obs + (size_t)g * GROWS * 512;
    gemm_bf16<1, true><<<dim3(16, GROWS / 64), 256, 0, stream>>>(
        (const void*)obs_g, E1T, enc_b1, E1C, 512, 512, 512, 1024);
    gemm_bf16<1, false><<<dim3(16, GROWS / 64), 256, 0, stream>>>(
        (const void*)E1C, E2T, enc_b2, EMBC, 1024, 1024, 1024, 1024);
    gemm_bf16<2, false><<<dim3(8, GROWS / 64), 256, 0, stream>>>(
        (const void*)EMBC, PET, post_b, POSTE + (size_t)g * GROWS * 512, 1024, 1024, 1024, 512);
  }

  // Phase B: one flag-synced persistent launch per group (normal launch),
  // then per-group heads.
  float* acckl = ACC + 2;
  for (int g = 0; g < NGRP; ++g) {
    int g0 = g * TGRP;
    phaseb_group_kernel<<<256, 256, 0, stream>>>(
        g0, HB, WHT, prior_b, POSTE, eps, actions, dones, WIHT,
        gru_bih, gru_bhh, G, XBUF, H, FEATC, acckl, FLAGS);
    gemm_bf16<1, false><<<dim3(32, GROWS / 64), 256, 0, stream>>>(
        (const void*)FEATC, WDRT, BDR, DR1C, 1280, 1280, 1280, 2048);
    decobs_loss_kernel<<<dim3(8, GROWS / 64), 256, 0, stream>>>(
        DR1C, DW2T, dec_b2, obs + ((size_t)g * TGRP + 1) * NB * 512, ACC);
    rew_loss_kernel<<<GROWS / 4, 256, 0, stream>>>(
        DR1C + 1024, rew_w2, rew_b2, rewards + (size_t)g * TGRP * NB, ACC);
  }

  finalize_kernel<<<1, 1, 0, stream>>>(ACC, out);
}

// Round 5
// 4883.468 us; speedup vs baseline: 1.9953x; 1.9953x over previous
//
#include <hip/hip_runtime.h>
#include <math.h>

// ---------------------------------------------------------------------------
// WorldModel RSSM forward losses — R10.
// R9 hung: flags padded to 128B apart span 225 ints but phase-0 zeroed only
// 64 -> flagB[1..3] garbage -> stage-1 spin deadlock. R10 zeroes the whole
// 256-int flag region. Design unchanged from R9:
//  * persistent per-group Phase B (9 launches), per-stripe flag dataflow.
//  * cross-block tensors (HB, xbuf, G) via RELAXED agent-scope sc1 ops
//    (coherence point), read-only weights via normal cached loads (L2 warm).
//  * spins RELAXED + s_sleep (no buffer_inv); ordering via __syncthreads
//    vmcnt drain before the relaxed flag fetch_add.
// ---------------------------------------------------------------------------

namespace {

typedef unsigned short ushort;
typedef unsigned int uint;
typedef unsigned long long u64;
typedef __attribute__((ext_vector_type(8))) short short8;   // 8 bf16 in 4 VGPRs
typedef __attribute__((ext_vector_type(4))) float f32x4;

constexpr int TSTEPS = 63;
constexpr int NB     = 256;
constexpr int NACT   = 32;
constexpr int NROWS  = TSTEPS * NB;   // 16128
constexpr int TGRP   = 7;
constexpr int NGRP   = 9;
constexpr int GROWS  = TGRP * NB;     // 1792 = 28*64

// ---- workspace layout (floats) --------------------------------------------
constexpr size_t OFF_POSTE = 0;                                     // f32 16128x512
constexpr size_t OFF_OBSB  = OFF_POSTE + (size_t)NROWS * 512;       // (unused)
constexpr size_t OFF_E1C   = OFF_OBSB + (size_t)GROWS * 512 / 2;    // u16 1792x1024
constexpr size_t OFF_EMBC  = OFF_E1C + (size_t)GROWS * 1024 / 2;    // u16 1792x1024
constexpr size_t OFF_FEATC = OFF_EMBC + (size_t)GROWS * 1024 / 2;   // u16 1792x1280
constexpr size_t OFF_DR1C  = OFF_FEATC + (size_t)GROWS * 1280 / 2;  // u16 1792x2048
constexpr size_t OFF_WHT   = OFF_DR1C + (size_t)GROWS * 2048 / 2;   // u16 4096x1024
constexpr size_t OFF_WIHT  = OFF_WHT + (size_t)4096 * 1024 / 2;     // u16 3072x288
constexpr size_t OFF_WDRT  = OFF_WIHT + (size_t)3072 * 288 / 2;     // u16 2048x1280
constexpr size_t OFF_E1T   = OFF_WDRT + (size_t)2048 * 1280 / 2;    // u16 1024x512
constexpr size_t OFF_E2T   = OFF_E1T + (size_t)1024 * 512 / 2;      // u16 1024x1024
constexpr size_t OFF_PET   = OFF_E2T + (size_t)1024 * 1024 / 2;     // u16 512x1024
constexpr size_t OFF_DW2T  = OFF_PET + (size_t)512 * 1024 / 2;      // u16 512x1024
constexpr size_t OFF_BDR   = OFF_DW2T + (size_t)512 * 1024 / 2;     // f32 2048
constexpr size_t OFF_G     = OFF_BDR + 2048;                        // f32 256x3072
constexpr size_t OFF_H     = OFF_G + (size_t)NB * 3072;             // f32 256x1024
constexpr size_t OFF_HB    = OFF_H + (size_t)NB * 1024;             // u16 256x1024
constexpr size_t OFF_ACC   = OFF_HB + (size_t)NB * 1024 / 2;        // f32 16
constexpr size_t OFF_XBUF  = OFF_ACC + 16;                          // u16 256x288
constexpr size_t OFF_FLAGS = OFF_XBUF + (size_t)NB * 288 / 2;       // i32 256 (padded)

__device__ __forceinline__ ushort f2bf(float f) {
  unsigned int u = __float_as_uint(f);
  unsigned int r = (u + 0x7fffu + ((u >> 16) & 1u)) >> 16;
  return (ushort)r;
}
__device__ __forceinline__ float bf2f(ushort u) {
  return __uint_as_float((unsigned int)u << 16);
}

// ---- device-coherent (sc1) relaxed access helpers -------------------------
__device__ __forceinline__ u64 ld_coh_u64(const void* p) {
  return __hip_atomic_load((u64*)p, __ATOMIC_RELAXED, __HIP_MEMORY_SCOPE_AGENT);
}
__device__ __forceinline__ void st_coh_u32(void* p, uint v) {
  __hip_atomic_store((uint*)p, v, __ATOMIC_RELAXED, __HIP_MEMORY_SCOPE_AGENT);
}
__device__ __forceinline__ void st_coh_f32(float* p, float v) {
  __hip_atomic_store(p, v, __ATOMIC_RELAXED, __HIP_MEMORY_SCOPE_AGENT);
}
__device__ __forceinline__ float ld_coh_f32(const float* p) {
  return __hip_atomic_load((float*)p, __ATOMIC_RELAXED, __HIP_MEMORY_SCOPE_AGENT);
}
__device__ __forceinline__ int4 mk_int4(u64 a, u64 b) {
  int4 v;
  v.x = (int)(uint)a; v.y = (int)(uint)(a >> 32);
  v.z = (int)(uint)b; v.w = (int)(uint)(b >> 32);
  return v;
}

__global__ void zero_kernel(float* p, int n) {
  int i = blockIdx.x * 256 + threadIdx.x;
  if (i < n) p[i] = 0.f;
}

__global__ void f2bf_kernel(const float* __restrict__ in, ushort* __restrict__ out, int n) {
  int i = blockIdx.x * 256 + threadIdx.x;
  if (i < n) out[i] = f2bf(in[i]);
}

// WHT[n][k]. n<1024: latent-permuted — quad q=(n>>4)&3 selects pm/pl/qm/ql,
// s = (n>>6)*16 + (n&15). n>=1024: whh[n-1024][k] (gh part).
__global__ void build_wht(const float* __restrict__ prior_w, const float* __restrict__ post_w,
                          const float* __restrict__ whh, ushort* __restrict__ out) {
  int idx = blockIdx.x * 256 + threadIdx.x;  // 4096*1024
  int n = idx >> 10, k = idx & 1023;
  float v;
  if (n < 1024) {
    int q = (n >> 4) & 3;
    int s = ((n >> 6) << 4) | (n & 15);
    v = (q == 0) ? prior_w[k * 512 + s]
      : (q == 1) ? prior_w[k * 512 + 256 + s]
      : (q == 2) ? post_w[k * 512 + s]
                 : post_w[k * 512 + 256 + s];
  } else {
    v = whh[(size_t)(n - 1024) * 1024 + k];
  }
  out[idx] = f2bf(v);
}

// out[c*ldo + r] = bf16(in[r*ldi + c]); grid (C/32, R/32)
__global__ void trans_conv(const float* __restrict__ in, ushort* __restrict__ out,
                           int ldi, int ldo) {
  __shared__ float tile[32][33];
  int r0 = blockIdx.y * 32, c0 = blockIdx.x * 32;
  int tx = threadIdx.x & 31, ty = threadIdx.x >> 5;
#pragma unroll
  for (int p = 0; p < 4; ++p)
    tile[ty + p * 8][tx] = in[(size_t)(r0 + ty + p * 8) * ldi + c0 + tx];
  __syncthreads();
#pragma unroll
  for (int p = 0; p < 4; ++p)
    out[(size_t)(c0 + ty + p * 8) * ldo + r0 + tx] = f2bf(tile[tx][ty + p * 8]);
}

__global__ void build_bdr(const float* __restrict__ dec_b1, const float* __restrict__ rew_b1,
                          float* __restrict__ bdr) {
  int i = blockIdx.x * 256 + threadIdx.x;  // 2048
  bdr[i] = (i < 1024) ? dec_b1[i] : rew_b1[i - 1024];
}

// ---------------------------------------------------------------------------
// Phase A/C bf16 GEMM (R6 body, proven): 64x64 tile, 4 waves, BK=32, LDS
// stride 40, register prefetch + LDS double buffer (one barrier/iter).
// EPI: 1 = +bias, relu, store bf16; 2 = +bias, store f32.
// ---------------------------------------------------------------------------
template <int EPI, bool AF32>
__global__ __launch_bounds__(256) void gemm_bf16(
    const void* __restrict__ Av, const ushort* __restrict__ BT,
    const float* __restrict__ bias, void* __restrict__ Cv,
    int K, int lda, int ldb, int ldc) {
  __shared__ __align__(16) ushort As[2][64 * 40];
  __shared__ __align__(16) ushort Bs[2][64 * 40];
  int tid = threadIdx.x;
  int wave = tid >> 6, lane = tid & 63;
  int quad = lane >> 4, l15 = lane & 15;
  int m0 = blockIdx.y * 64, n0 = blockIdx.x * 64;
  int sr = tid >> 2, sc = (tid & 3) * 8;
  const ushort* agb = (const ushort*)Av + (size_t)(m0 + sr) * lda + sc;
  const float*  agf = (const float*)Av + (size_t)(m0 + sr) * lda + sc;
  const ushort* bgp = BT + (size_t)(n0 + sr) * ldb + sc;
  int4 pa0, pa1, pb;
  if (AF32) { pa0 = *(const int4*)agf; pa1 = *(const int4*)(agf + 4); }
  else      { pa0 = *(const int4*)agb; }
  pb = *(const int4*)bgp;
  f32x4 acc[4] = {};
  int buf = 0;
  for (int k0 = 0; k0 < K; k0 += 32, buf ^= 1) {
    int4 st;
    if (AF32) {
      float f[8];
      *(int4*)&f[0] = pa0; *(int4*)&f[4] = pa1;
      ushort u[8];
#pragma unroll
      for (int i = 0; i < 8; ++i) u[i] = f2bf(f[i]);
      st = *(const int4*)u;
    } else {
      st = pa0;
    }
    *(int4*)&As[buf][sr * 40 + sc] = st;
    *(int4*)&Bs[buf][sr * 40 + sc] = pb;
    __syncthreads();
    int kn = k0 + 32;
    if (kn < K) {
      if (AF32) { pa0 = *(const int4*)(agf + kn); pa1 = *(const int4*)(agf + kn + 4); }
      else      { pa0 = *(const int4*)(agb + kn); }
      pb = *(const int4*)(bgp + kn);
    }
    short8 a = *(const short8*)&As[buf][(wave * 16 + l15) * 40 + quad * 8];
#pragma unroll
    for (int c = 0; c < 4; ++c) {
      short8 b = *(const short8*)&Bs[buf][(c * 16 + l15) * 40 + quad * 8];
      acc[c] = __builtin_amdgcn_mfma_f32_16x16x32_bf16(a, b, acc[c], 0, 0, 0);
    }
  }
#pragma unroll
  for (int c = 0; c < 4; ++c) {
#pragma unroll
    for (int r = 0; r < 4; ++r) {
      size_t row = m0 + wave * 16 + quad * 4 + r;
      int col = n0 + c * 16 + l15;
      float v = acc[c][r] + bias[col];
      if (EPI == 1) v = fmaxf(v, 0.f);
      if (EPI == 1) ((ushort*)Cv)[row * ldc + col] = f2bf(v);
      else ((float*)Cv)[row * ldc + col] = v;
    }
  }
}

// ---------------------------------------------------------------------------
// R10 Phase B: persistent per-group kernel, software-coherent flag dataflow.
// grid 256 x 256thr. bid = m*64 + n1 (m: 4 batch stripes x 64 rows, n1: 64
// n-tiles of WHT's 4096 cols).
// flags (padded 128B): flagA[m]=flags[m*32] stage-1 completions (64/step),
//                      flagB[m]=flags[128+m*32] stage-2 completions (16/step).
// Monotonic across steps and group launches; zeroed once per graph replay.
// ---------------------------------------------------------------------------
__global__ __launch_bounds__(256) void phaseb_group_kernel(
    int g0,
    ushort* __restrict__ HB, const ushort* __restrict__ WHT,
    const float* __restrict__ prior_b, const float* __restrict__ poste,
    const float* __restrict__ eps, const float* __restrict__ actions,
    const unsigned char* __restrict__ dones,
    const ushort* __restrict__ wiht, const float* __restrict__ bih,
    const float* __restrict__ bhh,
    float* __restrict__ G, ushort* __restrict__ xbuf,
    float* __restrict__ H, ushort* __restrict__ featc,
    float* __restrict__ acc_kl, int* __restrict__ flags) {
  __shared__ __align__(16) char smem[40960];
  ushort* As1 = (ushort*)smem;              // [2][64*72]
  ushort* Bs1 = (ushort*)(smem + 18432);    // [2][64*72]
  ushort* As2 = (ushort*)smem;              // [2][64*40]
  ushort* Bs2 = (ushort*)(smem + 10240);    // [2][3][64*40]

  int tid = threadIdx.x;
  int wave = tid >> 6, lane = tid & 63;
  int quad = lane >> 4, l15 = lane & 15;
  int bid = blockIdx.x;
  int n1 = bid & 63, m = bid >> 6;
  int m0 = m * 64, n01 = n1 * 64;
  int* flagA = &flags[m * 32];         // 128B apart
  int* flagB = &flags[128 + m * 32];

  // stage-1 staging addresses (A coherent, B normal/cached)
  int sr1 = tid >> 2, sc1 = (tid & 3) * 16;
  const ushort* agp1 = HB + (size_t)(m0 + sr1) * 1024 + sc1;
  const ushort* bgp1 = WHT + (size_t)(n01 + sr1) * 1024 + sc1;
  // stage-2 staging addresses (used when n1 < 16)
  int sr2 = tid >> 2, sc2 = (tid & 3) * 8;
  const ushort* agp2 = xbuf + (size_t)(m0 + sr2) * 288 + sc2;
  const ushort* bgp2 = wiht + (size_t)(n01 + sr2) * 288 + sc2;

  for (int tt = 0; tt < TGRP; ++tt) {
    int t = g0 + tt;
    // ---- wait: HB for step t complete (relaxed spin, no cache ops) -------
    if (tid == 0) {
      while (__hip_atomic_load(flagB, __ATOMIC_RELAXED, __HIP_MEMORY_SCOPE_AGENT) < 16 * t)
        __builtin_amdgcn_s_sleep(4);
    }
    __syncthreads();
    // ---------------- stage 1: HB @ WHT (K=1024, BK=64, prefetch 2) -------
    {
      u64 pa[2][4]; int4 pb[2][2];
#pragma unroll
      for (int s2 = 0; s2 < 2; ++s2) {
        const ushort* ap = agp1 + s2 * 64;
        pa[s2][0] = ld_coh_u64(ap);      pa[s2][1] = ld_coh_u64(ap + 4);
        pa[s2][2] = ld_coh_u64(ap + 8);  pa[s2][3] = ld_coh_u64(ap + 12);
        pb[s2][0] = *(const int4*)(bgp1 + s2 * 64);
        pb[s2][1] = *(const int4*)(bgp1 + s2 * 64 + 8);
      }
      f32x4 acc[4] = {};
      for (int k0 = 0; k0 < 1024; k0 += 64) {
        int cur = (k0 >> 6) & 1;
        ushort* as = As1 + cur * 4608;
        ushort* bs = Bs1 + cur * 4608;
        *(int4*)&as[sr1 * 72 + sc1]     = mk_int4(pa[cur][0], pa[cur][1]);
        *(int4*)&as[sr1 * 72 + sc1 + 8] = mk_int4(pa[cur][2], pa[cur][3]);
        *(int4*)&bs[sr1 * 72 + sc1]     = pb[cur][0];
        *(int4*)&bs[sr1 * 72 + sc1 + 8] = pb[cur][1];
        __syncthreads();
        int kf = k0 + 128;
        if (kf < 1024) {
          const ushort* ap = agp1 + kf;
          pa[cur][0] = ld_coh_u64(ap);      pa[cur][1] = ld_coh_u64(ap + 4);
          pa[cur][2] = ld_coh_u64(ap + 8);  pa[cur][3] = ld_coh_u64(ap + 12);
          pb[cur][0] = *(const int4*)(bgp1 + kf);
          pb[cur][1] = *(const int4*)(bgp1 + kf + 8);
        }
#pragma unroll
        for (int kk = 0; kk < 2; ++kk) {
          short8 a = *(const short8*)&as[(wave * 16 + l15) * 72 + kk * 32 + quad * 8];
#pragma unroll
          for (int c = 0; c < 4; ++c) {
            short8 b = *(const short8*)&bs[(c * 16 + l15) * 72 + kk * 32 + quad * 8];
            acc[c] = __builtin_amdgcn_mfma_f32_16x16x32_bf16(a, b, acc[c], 0, 0, 0);
          }
        }
      }
      if (n1 < 16) {
        // latent epilogue: acc[0..3] = pm,pl,qm,ql for s = n1*16 + l15
        int s = (n01 >> 2) + l15;
        float kl_sum = 0.f;
#pragma unroll
        for (int r = 0; r < 4; ++r) {
          int b = m0 + wave * 16 + quad * 4 + r;
          size_t row = (size_t)t * NB + b;
          float pm = acc[0][r] + prior_b[s];
          float pl = acc[1][r] + prior_b[256 + s];
          float qm = acc[2][r] + poste[row * 512 + s];
          float ql = acc[3][r] + poste[row * 512 + 256 + s];
          float e = eps[row * 256 + s];
          float z = qm + e * expf(ql);
          featc[(size_t)(tt * NB + b) * 1280 + 1024 + s] = f2bf(z);  // cross-kernel
          // xbuf: cross-block -> paired coherent u32 store
          float zn = __shfl_xor(z, 1);
          if ((l15 & 1) == 0)
            st_coh_u32(&xbuf[b * 288 + s],
                       (uint)f2bf(z) | ((uint)f2bf(zn) << 16));
          if (s < NACT) {
            float av = actions[row * NACT + s];
            float avn = __shfl_xor(av, 1);
            if ((l15 & 1) == 0)
              st_coh_u32(&xbuf[b * 288 + 256 + s],
                         (uint)f2bf(av) | ((uint)f2bf(avn) << 16));
          }
          float vq = expf(2.f * ql), vp = expf(2.f * pl);
          float dm = qm - pm;
          kl_sum += pl - ql + (vq + dm * dm) / (vp + 1e-8f) - 1.f;
        }
        for (int off = 32; off > 0; off >>= 1) kl_sum += __shfl_down(kl_sum, off);
        if (lane == 0) atomicAdd(acc_kl, 0.5f * kl_sum);
      } else {
        int ng = n01 - 1024;
#pragma unroll
        for (int c = 0; c < 4; ++c)
#pragma unroll
          for (int r = 0; r < 4; ++r) {
            int b = m0 + wave * 16 + quad * 4 + r;
            st_coh_f32(&G[(size_t)b * 3072 + ng + c * 16 + l15], acc[c][r]);
          }
      }
    }
    __syncthreads();  // drains vmcnt: all coherent stores globally visible
    if (tid == 0)
      __hip_atomic_fetch_add(flagA, 1, __ATOMIC_RELAXED, __HIP_MEMORY_SCOPE_AGENT);
    // ---------------- stage 2 (n1<16): GRU gates + state update -----------
    if (n1 < 16) {
      if (tid == 0) {
        while (__hip_atomic_load(flagA, __ATOMIC_RELAXED, __HIP_MEMORY_SCOPE_AGENT) < 64 * (t + 1))
          __builtin_amdgcn_s_sleep(4);
      }
      __syncthreads();
      // A (xbuf) coherent prefetch-2; B (wiht) normal prefetch-2.
      u64 pa2[2][2]; int4 pb2[2][3];
#pragma unroll
      for (int s2 = 0; s2 < 2; ++s2) {
        const ushort* ap = agp2 + s2 * 32;
        pa2[s2][0] = ld_coh_u64(ap); pa2[s2][1] = ld_coh_u64(ap + 4);
#pragma unroll
        for (int gg = 0; gg < 3; ++gg)
          pb2[s2][gg] = *(const int4*)(bgp2 + (size_t)gg * 1024 * 288 + s2 * 32);
      }
      f32x4 accv[3][4] = {};
      for (int k0 = 0; k0 < 288; k0 += 32) {
        int cur = (k0 >> 5) & 1;
        ushort* as = As2 + cur * 2560;
        ushort* bs = Bs2 + cur * 7680;
        *(int4*)&as[sr2 * 40 + sc2] = mk_int4(pa2[cur][0], pa2[cur][1]);
#pragma unroll
        for (int gg = 0; gg < 3; ++gg)
          *(int4*)&bs[gg * 2560 + sr2 * 40 + sc2] = pb2[cur][gg];
        __syncthreads();
        int kf = k0 + 64;
        if (kf < 288) {
          const ushort* ap = agp2 + kf;
          pa2[cur][0] = ld_coh_u64(ap); pa2[cur][1] = ld_coh_u64(ap + 4);
#pragma unroll
          for (int gg = 0; gg < 3; ++gg)
            pb2[cur][gg] = *(const int4*)(bgp2 + (size_t)gg * 1024 * 288 + kf);
        }
        short8 a = *(const short8*)&as[(wave * 16 + l15) * 40 + quad * 8];
#pragma unroll
        for (int gg = 0; gg < 3; ++gg) {
#pragma unroll
          for (int c = 0; c < 4; ++c) {
            short8 b = *(const short8*)&bs[gg * 2560 + (c * 16 + l15) * 40 + quad * 8];
            accv[gg][c] = __builtin_amdgcn_mfma_f32_16x16x32_bf16(a, b, accv[gg][c], 0, 0, 0);
          }
        }
      }
#pragma unroll
      for (int c = 0; c < 4; ++c) {
#pragma unroll
        for (int r = 0; r < 4; ++r) {
          int b_idx = m0 + wave * 16 + quad * 4 + r;
          int j = n01 + c * 16 + l15;
          const float* g = G + (size_t)b_idx * 3072;
          float ir = accv[0][c][r] + bih[j];
          float iz = accv[1][c][r] + bih[1024 + j];
          float in_ = accv[2][c][r] + bih[2048 + j];
          float hr = ld_coh_f32(&g[j]) + bhh[j];
          float hz = ld_coh_f32(&g[1024 + j]) + bhh[1024 + j];
          float hn = ld_coh_f32(&g[2048 + j]) + bhh[2048 + j];
          float rg = 1.f / (1.f + expf(-(ir + hr)));
          float u = 1.f / (1.f + expf(-(iz + hz)));
          float n = tanhf(in_ + rg * hn);
          float hprev = H[b_idx * 1024 + j];   // same-block across steps
          float hnext = (1.f - u) * n + u * hprev;
          featc[(size_t)(tt * NB + b_idx) * 1280 + j] = f2bf(hnext);
          float mask = 1.f - (float)dones[t * NB + b_idx];
          float hm = hnext * mask;
          H[b_idx * 1024 + j] = hm;            // normal (same-block reuse)
          float hmn = __shfl_xor(hm, 1);       // HB cross-block -> coherent
          if ((l15 & 1) == 0)
            st_coh_u32(&HB[b_idx * 1024 + j],
                       (uint)f2bf(hm) | ((uint)f2bf(hmn) << 16));
        }
      }
      __syncthreads();  // drains vmcnt: HB coherent stores visible
      if (tid == 0)
        __hip_atomic_fetch_add(flagB, 1, __ATOMIC_RELAXED, __HIP_MEMORY_SCOPE_AGENT);
    }
  }
}

// ---------------------------------------------------------------------------
// Decoder-out GEMM + fused recon loss (R6 body).
// ---------------------------------------------------------------------------
__global__ __launch_bounds__(256) void decobs_loss_kernel(
    const ushort* __restrict__ A, const ushort* __restrict__ BT,
    const float* __restrict__ bias, const float* __restrict__ obs_next_g,
    float* __restrict__ acc) {
  __shared__ __align__(16) ushort As[2][64 * 40];
  __shared__ __align__(16) ushort Bs[2][64 * 40];
  int tid = threadIdx.x;
  int wave = tid >> 6, lane = tid & 63;
  int quad = lane >> 4, l15 = lane & 15;
  int m0 = blockIdx.y * 64, n0 = blockIdx.x * 64;
  int sr = tid >> 2, sc = (tid & 3) * 8;
  const ushort* agp = A + (size_t)(m0 + sr) * 2048 + sc;
  const ushort* bgp = BT + (size_t)(n0 + sr) * 1024 + sc;
  int4 pa = *(const int4*)agp;
  int4 pb = *(const int4*)bgp;
  f32x4 accm[4] = {};
  int buf = 0;
  for (int k0 = 0; k0 < 1024; k0 += 32, buf ^= 1) {
    *(int4*)&As[buf][sr * 40 + sc] = pa;
    *(int4*)&Bs[buf][sr * 40 + sc] = pb;
    __syncthreads();
    int kn = k0 + 32;
    if (kn < 1024) {
      pa = *(const int4*)(agp + kn);
      pb = *(const int4*)(bgp + kn);
    }
    short8 a = *(const short8*)&As[buf][(wave * 16 + l15) * 40 + quad * 8];
#pragma unroll
    for (int c = 0; c < 4; ++c) {
      short8 b = *(const short8*)&Bs[buf][(c * 16 + l15) * 40 + quad * 8];
      accm[c] = __builtin_amdgcn_mfma_f32_16x16x32_bf16(a, b, accm[c], 0, 0, 0);
    }
  }
  float local = 0.f;
#pragma unroll
  for (int c = 0; c < 4; ++c) {
#pragma unroll
    for (int r = 0; r < 4; ++r) {
      size_t row = m0 + wave * 16 + quad * 4 + r;
      int col = n0 + c * 16 + l15;
      float v = accm[c][r] + bias[col];
      float d = v - obs_next_g[row * 512 + col];
      local += d * d;
    }
  }
  __shared__ float red[256];
  red[tid] = local;
  __syncthreads();
  for (int st = 128; st > 0; st >>= 1) {
    if (tid < st) red[tid] += red[tid + st];
    __syncthreads();
  }
  if (tid == 0) atomicAdd(&acc[0], red[0]);
}

// Reward matvec + loss. R1 = DR1C + 1024 (bf16, row stride 2048).
__global__ __launch_bounds__(256) void rew_loss_kernel(
    const ushort* __restrict__ R1, const float* __restrict__ w2,
    const float* __restrict__ b2, const float* __restrict__ rewards_g,
    float* __restrict__ acc) {
  int wave = threadIdx.x >> 6;
  int lane = threadIdx.x & 63;
  int row = blockIdx.x * 4 + wave;
  const ushort* rp = R1 + (size_t)row * 2048;
  float s = 0.f;
#pragma unroll
  for (int i = 0; i < 16; ++i) s += bf2f(rp[lane + 64 * i]) * w2[lane + 64 * i];
  for (int off = 32; off > 0; off >>= 1) s += __shfl_down(s, off);
  if (lane == 0) {
    float d = s + b2[0] - rewards_g[row];
    atomicAdd(&acc[1], d * d);
  }
}

__global__ void finalize_kernel(const float* __restrict__ acc, float* __restrict__ out) {
  float recon = acc[0] / ((float)NROWS * 512.f);
  float rew = acc[1] / (float)NROWS;
  float kl = acc[2] / (float)NROWS;
  out[0] = recon + rew + kl;
  out[1] = recon;
  out[2] = rew;
  out[3] = kl;
}

}  // namespace

extern "C" void kernel_launch(void* const* d_in, const int* in_sizes, int n_in,
                              void* d_out, int out_size, void* d_ws, size_t ws_size,
                              hipStream_t stream) {
  const float* obs     = (const float*)d_in[0];
  const float* actions = (const float*)d_in[1];
  const float* rewards = (const float*)d_in[2];
  const unsigned char* dones = (const unsigned char*)d_in[3];
  const float* eps     = (const float*)d_in[4];
  const float* enc_w1  = (const float*)d_in[5];
  const float* enc_b1  = (const float*)d_in[6];
  const float* enc_w2  = (const float*)d_in[7];
  const float* enc_b2  = (const float*)d_in[8];
  const float* gru_wih = (const float*)d_in[9];
  const float* gru_whh = (const float*)d_in[10];
  const float* gru_bih = (const float*)d_in[11];
  const float* gru_bhh = (const float*)d_in[12];
  const float* prior_w = (const float*)d_in[13];
  const float* prior_b = (const float*)d_in[14];
  const float* post_w  = (const float*)d_in[15];
  const float* post_b  = (const float*)d_in[16];
  const float* dec_w1  = (const float*)d_in[17];
  const float* dec_b1  = (const float*)d_in[18];
  const float* dec_w2  = (const float*)d_in[19];
  const float* dec_b2  = (const float*)d_in[20];
  const float* rew_w1  = (const float*)d_in[21];
  const float* rew_b1  = (const float*)d_in[22];
  const float* rew_w2  = (const float*)d_in[23];
  const float* rew_b2  = (const float*)d_in[24];
  float* out = (float*)d_out;
  float* ws = (float*)d_ws;

  float*  POSTE = ws + OFF_POSTE;
  ushort* E1C   = (ushort*)(ws + OFF_E1C);
  ushort* EMBC  = (ushort*)(ws + OFF_EMBC);
  ushort* FEATC = (ushort*)(ws + OFF_FEATC);
  ushort* DR1C  = (ushort*)(ws + OFF_DR1C);
  ushort* WHT   = (ushort*)(ws + OFF_WHT);
  ushort* WIHT  = (ushort*)(ws + OFF_WIHT);
  ushort* WDRT  = (ushort*)(ws + OFF_WDRT);
  ushort* E1T   = (ushort*)(ws + OFF_E1T);
  ushort* E2T   = (ushort*)(ws + OFF_E2T);
  ushort* PET   = (ushort*)(ws + OFF_PET);
  ushort* DW2T  = (ushort*)(ws + OFF_DW2T);
  float*  BDR   = ws + OFF_BDR;
  float*  G     = ws + OFF_G;
  float*  H     = ws + OFF_H;
  ushort* HB    = (ushort*)(ws + OFF_HB);
  float*  ACC   = ws + OFF_ACC;
  ushort* XBUF  = (ushort*)(ws + OFF_XBUF);
  int*    FLAGS = (int*)(ws + OFF_FLAGS);

  // Phase 0: zero H + HB + ACC + XBUF + FLAGS (contiguous; FLAGS = 256 ints
  // = 256 floats worth — R9's bug was zeroing only 64).
  {
    int nzero = NB * 1024 + NB * 512 + 16 + NB * 288 / 2 + 256;
    zero_kernel<<<(nzero + 255) / 256, 256, 0, stream>>>(H, nzero);
  }
  build_wht<<<4096 * 1024 / 256, 256, 0, stream>>>(prior_w, post_w, gru_whh, WHT);
  f2bf_kernel<<<(3072 * 288) / 256, 256, 0, stream>>>(gru_wih, WIHT, 3072 * 288);
  trans_conv<<<dim3(1024 / 32, 1280 / 32), 256, 0, stream>>>(dec_w1, WDRT, 1024, 1280);
  trans_conv<<<dim3(1024 / 32, 1280 / 32), 256, 0, stream>>>(rew_w1, WDRT + (size_t)1024 * 1280, 1024, 1280);
  trans_conv<<<dim3(1024 / 32, 512 / 32), 256, 0, stream>>>(enc_w1, E1T, 1024, 512);
  trans_conv<<<dim3(1024 / 32, 1024 / 32), 256, 0, stream>>>(enc_w2, E2T, 1024, 1024);
  trans_conv<<<dim3(512 / 32, 1024 / 32), 256, 0, stream>>>(post_w + (size_t)1024 * 512, PET, 512, 1024);
  trans_conv<<<dim3(512 / 32, 1024 / 32), 256, 0, stream>>>(dec_w2, DW2T, 512, 1024);
  build_bdr<<<8, 256, 0, stream>>>(dec_b1, rew_b1, BDR);

  // Phase A: encoder + posterior-from-emb, chunked per group.
  for (int g = 0; g < NGRP; ++g) {
    const float* obs_g = obs + (size_t)g * GROWS * 512;
    gemm_bf16<1, true><<<dim3(16, GROWS / 64), 256, 0, stream>>>(
        (const void*)obs_g, E1T, enc_b1, E1C, 512, 512, 512, 1024);
    gemm_bf16<1, false><<<dim3(16, GROWS / 64), 256, 0, stream>>>(
        (const void*)E1C, E2T, enc_b2, EMBC, 1024, 1024, 1024, 1024);
    gemm_bf16<2, false><<<dim3(8, GROWS / 64), 256, 0, stream>>>(
        (const void*)EMBC, PET, post_b, POSTE + (size_t)g * GROWS * 512, 1024, 1024, 1024, 512);
  }

  // Phase B: one persistent flag-synced launch per group, then heads.
  float* acckl = ACC + 2;
  for (int g = 0; g < NGRP; ++g) {
    int g0 = g * TGRP;
    phaseb_group_kernel<<<256, 256, 0, stream>>>(
        g0, HB, WHT, prior_b, POSTE, eps, actions, dones, WIHT,
        gru_bih, gru_bhh, G, XBUF, H, FEATC, acckl, FLAGS);
    gemm_bf16<1, false><<<dim3(32, GROWS / 64), 256, 0, stream>>>(
        (const void*)FEATC, WDRT, BDR, DR1C, 1280, 1280, 1280, 2048);
    decobs_loss_kernel<<<dim3(8, GROWS / 64), 256, 0, stream>>>(
        DR1C, DW2T, dec_b2, obs + ((size_t)g * TGRP + 1) * NB * 512, ACC);
    rew_loss_kernel<<<GROWS / 4, 256, 0, stream>>>(
        DR1C + 1024, rew_w2, rew_b2, rewards + (size_t)g * TGRP * NB, ACC);
  }

  finalize_kernel<<<1, 1, 0, stream>>>(ACC, out);
}

// Round 6
// 3056.035 us; speedup vs baseline: 3.1885x; 1.5980x over previous
//
#include <hip/hip_runtime.h>
#include <math.h>

// ---------------------------------------------------------------------------
// WorldModel RSSM forward losses — R11.
// R7-R10 post-mortem: ALL persistent Phase B variants (grid.sync, acquire
// flags, relaxed sc1 flags) are 420-1000us/group vs ~170us/group for plain
// per-step launches — on CDNA4 the cross-block producer/consumer path
// (coherence point, L2 bypass) costs more than kernel boundaries. Persistent
// abandoned. R11 = R6 structure (3044us) + two targeted fixes:
//  1) gemm_big<BM,EPI,AF32>: BMx128-tile GEMM (4 waves, 64-row wave tiles,
//     reg prefetch + LDS dbuf, stride-40) for the three biggest GEMMs:
//     obs@enc1 (64x128, grid 8x28), e1@enc2 (64x128, 8x28),
//     featc@WDRT (128x128, grid 16x14). 2-4x MFMA per staged byte vs 64x64.
//  2) build_wht latent half was 4M uncoalesced stride-512 4B reads ->
//     32x32 tiled permuted transpose; whh half -> plain coalesced f2bf.
// Phase B per-step kernels are bit-identical to R6 (proven, absmax 0).
// ---------------------------------------------------------------------------

namespace {

typedef unsigned short ushort;
typedef __attribute__((ext_vector_type(8))) short short8;   // 8 bf16 in 4 VGPRs
typedef __attribute__((ext_vector_type(4))) float f32x4;

constexpr int TSTEPS = 63;
constexpr int NB     = 256;
constexpr int NACT   = 32;
constexpr int NROWS  = TSTEPS * NB;   // 16128
constexpr int TGRP   = 7;
constexpr int NGRP   = 9;
constexpr int GROWS  = TGRP * NB;     // 1792 = 28*64

// ---- workspace layout (floats) --------------------------------------------
constexpr size_t OFF_POSTE = 0;                                     // f32 16128x512
constexpr size_t OFF_OBSB  = OFF_POSTE + (size_t)NROWS * 512;       // (unused)
constexpr size_t OFF_E1C   = OFF_OBSB + (size_t)GROWS * 512 / 2;    // u16 1792x1024
constexpr size_t OFF_EMBC  = OFF_E1C + (size_t)GROWS * 1024 / 2;    // u16 1792x1024
constexpr size_t OFF_FEATC = OFF_EMBC + (size_t)GROWS * 1024 / 2;   // u16 1792x1280
constexpr size_t OFF_DR1C  = OFF_FEATC + (size_t)GROWS * 1280 / 2;  // u16 1792x2048
constexpr size_t OFF_WHT   = OFF_DR1C + (size_t)GROWS * 2048 / 2;   // u16 4096x1024
constexpr size_t OFF_WIHT  = OFF_WHT + (size_t)4096 * 1024 / 2;     // u16 3072x288
constexpr size_t OFF_WDRT  = OFF_WIHT + (size_t)3072 * 288 / 2;     // u16 2048x1280
constexpr size_t OFF_E1T   = OFF_WDRT + (size_t)2048 * 1280 / 2;    // u16 1024x512
constexpr size_t OFF_E2T   = OFF_E1T + (size_t)1024 * 512 / 2;      // u16 1024x1024
constexpr size_t OFF_PET   = OFF_E2T + (size_t)1024 * 1024 / 2;     // u16 512x1024
constexpr size_t OFF_DW2T  = OFF_PET + (size_t)512 * 1024 / 2;      // u16 512x1024
constexpr size_t OFF_BDR   = OFF_DW2T + (size_t)512 * 1024 / 2;     // f32 2048
constexpr size_t OFF_G     = OFF_BDR + 2048;                        // f32 256x3072
constexpr size_t OFF_H     = OFF_G + (size_t)NB * 3072;             // f32 256x1024
constexpr size_t OFF_HB    = OFF_H + (size_t)NB * 1024;             // u16 256x1024
constexpr size_t OFF_ACC   = OFF_HB + (size_t)NB * 1024 / 2;        // f32 16
constexpr size_t OFF_XBUF  = OFF_ACC + 16;                          // u16 256x288

__device__ __forceinline__ ushort f2bf(float f) {
  unsigned int u = __float_as_uint(f);
  unsigned int r = (u + 0x7fffu + ((u >> 16) & 1u)) >> 16;
  return (ushort)r;
}
__device__ __forceinline__ float bf2f(ushort u) {
  return __uint_as_float((unsigned int)u << 16);
}

__global__ void zero_kernel(float* p, int n) {
  int i = blockIdx.x * 256 + threadIdx.x;
  if (i < n) p[i] = 0.f;
}

__global__ void f2bf_kernel(const float* __restrict__ in, ushort* __restrict__ out, int n) {
  int i = blockIdx.x * 256 + threadIdx.x;
  if (i < n) out[i] = f2bf(in[i]);
}

// WHT latent rows (n<1024): out[n][k] = src[k][c(n)] with
// q=(n>>4)&3 selecting pm/pl/qm/ql, s=((n>>6)<<4)|(n&15).
// Tiled 32x32 transpose: coalesced on both sides (src cols within a 32-band
// are two contiguous 16-runs). grid (K/32, N/32), 256 thr.
__global__ void build_wht_latent(const float* __restrict__ prior_w,
                                 const float* __restrict__ post_w,
                                 ushort* __restrict__ out) {
  __shared__ float tile[32][33];
  int k0 = blockIdx.x * 32, n0 = blockIdx.y * 32;
  int tx = threadIdx.x & 31, ty = threadIdx.x >> 5;  // ty 0..7
  int n = n0 + tx;
  int q = (n >> 4) & 3;
  int s = ((n >> 6) << 4) | (n & 15);
  const float* src = (q < 2) ? prior_w : post_w;
  int col = (q & 1) ? (256 + s) : s;
#pragma unroll
  for (int p = 0; p < 4; ++p)
    tile[ty + p * 8][tx] = src[(size_t)(k0 + ty + p * 8) * 512 + col];
  __syncthreads();
#pragma unroll
  for (int p = 0; p < 4; ++p)
    out[(size_t)(n0 + ty + p * 8) * 1024 + k0 + tx] = f2bf(tile[tx][ty + p * 8]);
}

// out[c*ldo + r] = bf16(in[r*ldi + c]); grid (C/32, R/32)
__global__ void trans_conv(const float* __restrict__ in, ushort* __restrict__ out,
                           int ldi, int ldo) {
  __shared__ float tile[32][33];
  int r0 = blockIdx.y * 32, c0 = blockIdx.x * 32;
  int tx = threadIdx.x & 31, ty = threadIdx.x >> 5;
#pragma unroll
  for (int p = 0; p < 4; ++p)
    tile[ty + p * 8][tx] = in[(size_t)(r0 + ty + p * 8) * ldi + c0 + tx];
  __syncthreads();
#pragma unroll
  for (int p = 0; p < 4; ++p)
    out[(size_t)(c0 + ty + p * 8) * ldo + r0 + tx] = f2bf(tile[tx][ty + p * 8]);
}

__global__ void build_bdr(const float* __restrict__ dec_b1, const float* __restrict__ rew_b1,
                          float* __restrict__ bdr) {
  int i = blockIdx.x * 256 + threadIdx.x;  // 2048
  bdr[i] = (i < 1024) ? dec_b1[i] : rew_b1[i - 1024];
}

// ---------------------------------------------------------------------------
// 64x64-tile GEMM (R6 body, proven) — kept for the posterior GEMM (N=512).
// ---------------------------------------------------------------------------
template <int EPI, bool AF32>
__global__ __launch_bounds__(256) void gemm_bf16(
    const void* __restrict__ Av, const ushort* __restrict__ BT,
    const float* __restrict__ bias, void* __restrict__ Cv,
    int K, int lda, int ldb, int ldc) {
  __shared__ __align__(16) ushort As[2][64 * 40];
  __shared__ __align__(16) ushort Bs[2][64 * 40];
  int tid = threadIdx.x;
  int wave = tid >> 6, lane = tid & 63;
  int quad = lane >> 4, l15 = lane & 15;
  int m0 = blockIdx.y * 64, n0 = blockIdx.x * 64;
  int sr = tid >> 2, sc = (tid & 3) * 8;
  const ushort* agb = (const ushort*)Av + (size_t)(m0 + sr) * lda + sc;
  const float*  agf = (const float*)Av + (size_t)(m0 + sr) * lda + sc;
  const ushort* bgp = BT + (size_t)(n0 + sr) * ldb + sc;
  int4 pa0, pa1, pb;
  if (AF32) { pa0 = *(const int4*)agf; pa1 = *(const int4*)(agf + 4); }
  else      { pa0 = *(const int4*)agb; }
  pb = *(const int4*)bgp;
  f32x4 acc[4] = {};
  int buf = 0;
  for (int k0 = 0; k0 < K; k0 += 32, buf ^= 1) {
    int4 st;
    if (AF32) {
      float f[8];
      *(int4*)&f[0] = pa0; *(int4*)&f[4] = pa1;
      ushort u[8];
#pragma unroll
      for (int i = 0; i < 8; ++i) u[i] = f2bf(f[i]);
      st = *(const int4*)u;
    } else {
      st = pa0;
    }
    *(int4*)&As[buf][sr * 40 + sc] = st;
    *(int4*)&Bs[buf][sr * 40 + sc] = pb;
    __syncthreads();
    int kn = k0 + 32;
    if (kn < K) {
      if (AF32) { pa0 = *(const int4*)(agf + kn); pa1 = *(const int4*)(agf + kn + 4); }
      else      { pa0 = *(const int4*)(agb + kn); }
      pb = *(const int4*)(bgp + kn);
    }
    short8 a = *(const short8*)&As[buf][(wave * 16 + l15) * 40 + quad * 8];
#pragma unroll
    for (int c = 0; c < 4; ++c) {
      short8 b = *(const short8*)&Bs[buf][(c * 16 + l15) * 40 + quad * 8];
      acc[c] = __builtin_amdgcn_mfma_f32_16x16x32_bf16(a, b, acc[c], 0, 0, 0);
    }
  }
#pragma unroll
  for (int c = 0; c < 4; ++c) {
#pragma unroll
    for (int r = 0; r < 4; ++r) {
      size_t row = m0 + wave * 16 + quad * 4 + r;
      int col = n0 + c * 16 + l15;
      float v = acc[c][r] + bias[col];
      if (EPI == 1) v = fmaxf(v, 0.f);
      if (EPI == 1) ((ushort*)Cv)[row * ldc + col] = f2bf(v);
      else ((float*)Cv)[row * ldc + col] = v;
    }
  }
}

// ---------------------------------------------------------------------------
// R11: BMx128-tile GEMM. 4 waves; each wave owns 64 rows x (128/WN) cols:
//   BM=64 : waves 1x4, wave tile 64x32 (MT=4, NT=2)
//   BM=128: waves 2x2, wave tile 64x64 (MT=4, NT=4)
// BK=32, stride-40 LDS (2-way bank pattern = free), register prefetch +
// LDS double buffer, one barrier per K-iter. Same fragment math as the
// proven 64x64 kernel. EPI: 1 = +bias relu bf16; 2 = +bias f32.
// ---------------------------------------------------------------------------
template <int BM, int EPI, bool AF32>
__global__ __launch_bounds__(256) void gemm_big(
    const void* __restrict__ Av, const ushort* __restrict__ BT,
    const float* __restrict__ bias, void* __restrict__ Cv,
    int K, int lda, int ldb, int ldc) {
  constexpr int BN = 128;
  constexpr int WM = BM / 64;         // 1 or 2
  constexpr int WN = 4 / WM;          // 4 or 2
  constexpr int NT = BN / WN / 16;    // 2 or 4
  __shared__ __align__(16) ushort As[2][BM * 40];
  __shared__ __align__(16) ushort Bs[2][BN * 40];
  int tid = threadIdx.x;
  int w = tid >> 6, lane = tid & 63;
  int quad = lane >> 4, l15 = lane & 15;
  int wm = (WM == 1) ? 0 : (w >> 1);
  int wn = (WM == 1) ? w : (w & 1);
  int m0 = blockIdx.y * BM, n0 = blockIdx.x * BN;
  int sar = (BM == 64) ? (tid >> 2) : (tid >> 1);
  int sac = (BM == 64) ? ((tid & 3) * 8) : ((tid & 1) * 16);
  int sbr = tid >> 1, sbc = (tid & 1) * 16;
  const ushort* agb = (const ushort*)Av + (size_t)(m0 + sar) * lda + sac;
  const float*  agf = (const float*)Av + (size_t)(m0 + sar) * lda + sac;
  const ushort* bgp = BT + (size_t)(n0 + sbr) * ldb + sbc;
  int4 pa0, pa1, pb0, pb1;
  if (AF32)         { pa0 = *(const int4*)agf; pa1 = *(const int4*)(agf + 4); }
  else if (BM == 64){ pa0 = *(const int4*)agb; }
  else              { pa0 = *(const int4*)agb; pa1 = *(const int4*)(agb + 8); }
  pb0 = *(const int4*)bgp; pb1 = *(const int4*)(bgp + 8);
  f32x4 acc[4][NT] = {};
  int buf = 0;
  for (int k0 = 0; k0 < K; k0 += 32, buf ^= 1) {
    if (AF32) {
      float f[8];
      *(int4*)&f[0] = pa0; *(int4*)&f[4] = pa1;
      ushort u[8];
#pragma unroll
      for (int i = 0; i < 8; ++i) u[i] = f2bf(f[i]);
      *(int4*)&As[buf][sar * 40 + sac] = *(const int4*)u;
    } else if (BM == 64) {
      *(int4*)&As[buf][sar * 40 + sac] = pa0;
    } else {
      *(int4*)&As[buf][sar * 40 + sac] = pa0;
      *(int4*)&As[buf][sar * 40 + sac + 8] = pa1;
    }
    *(int4*)&Bs[buf][sbr * 40 + sbc] = pb0;
    *(int4*)&Bs[buf][sbr * 40 + sbc + 8] = pb1;
    __syncthreads();
    int kn = k0 + 32;
    if (kn < K) {
      if (AF32)          { pa0 = *(const int4*)(agf + kn); pa1 = *(const int4*)(agf + kn + 4); }
      else if (BM == 64) { pa0 = *(const int4*)(agb + kn); }
      else               { pa0 = *(const int4*)(agb + kn); pa1 = *(const int4*)(agb + kn + 8); }
      pb0 = *(const int4*)(bgp + kn); pb1 = *(const int4*)(bgp + kn + 8);
    }
    short8 af[4], bfr[NT];
#pragma unroll
    for (int mt = 0; mt < 4; ++mt)
      af[mt] = *(const short8*)&As[buf][(wm * 64 + mt * 16 + l15) * 40 + quad * 8];
#pragma unroll
    for (int nt = 0; nt < NT; ++nt)
      bfr[nt] = *(const short8*)&Bs[buf][(wn * (BN / WN) + nt * 16 + l15) * 40 + quad * 8];
#pragma unroll
    for (int mt = 0; mt < 4; ++mt)
#pragma unroll
      for (int nt = 0; nt < NT; ++nt)
        acc[mt][nt] = __builtin_amdgcn_mfma_f32_16x16x32_bf16(af[mt], bfr[nt], acc[mt][nt], 0, 0, 0);
  }
#pragma unroll
  for (int mt = 0; mt < 4; ++mt)
#pragma unroll
    for (int nt = 0; nt < NT; ++nt)
#pragma unroll
      for (int r = 0; r < 4; ++r) {
        size_t row = m0 + wm * 64 + mt * 16 + quad * 4 + r;
        int col = n0 + wn * (BN / WN) + nt * 16 + l15;
        float v = acc[mt][nt][r] + bias[col];
        if (EPI == 1) { v = fmaxf(v, 0.f); ((ushort*)Cv)[row * ldc + col] = f2bf(v); }
        else ((float*)Cv)[row * ldc + col] = v;
      }
}

// ---------------------------------------------------------------------------
// Phase B kernel 1 (R6, proven): G = HB @ WHT (M=256, N=4096, K=1024), BK=64,
// register prefetch + LDS dbuf. blockIdx.x<16 -> latent-permuted cols, fused
// z/KL epilogue; others store gh to G.
// ---------------------------------------------------------------------------
__global__ __launch_bounds__(256) void step_g_kernel(
    int t, int tt, const ushort* __restrict__ HB, const ushort* __restrict__ WHT,
    const float* __restrict__ prior_b, const float* __restrict__ poste,
    const float* __restrict__ eps, const float* __restrict__ actions,
    float* __restrict__ G, ushort* __restrict__ xbuf,
    ushort* __restrict__ featc, float* __restrict__ acc_kl) {
  __shared__ __align__(16) ushort As[2][64 * 72];
  __shared__ __align__(16) ushort Bs[2][64 * 72];
  int tid = threadIdx.x;
  int wave = tid >> 6, lane = tid & 63;
  int quad = lane >> 4, l15 = lane & 15;
  int m0 = blockIdx.y * 64, n0 = blockIdx.x * 64;
  int sr = tid >> 2, sc = (tid & 3) * 16;
  const ushort* agp = HB + (size_t)(m0 + sr) * 1024 + sc;
  const ushort* bgp = WHT + (size_t)(n0 + sr) * 1024 + sc;
  int4 a0 = *(const int4*)agp, a1 = *(const int4*)(agp + 8);
  int4 b0 = *(const int4*)bgp, b1 = *(const int4*)(bgp + 8);
  f32x4 acc[4] = {};
  int buf = 0;
  for (int k0 = 0; k0 < 1024; k0 += 64, buf ^= 1) {
    *(int4*)&As[buf][sr * 72 + sc] = a0; *(int4*)&As[buf][sr * 72 + sc + 8] = a1;
    *(int4*)&Bs[buf][sr * 72 + sc] = b0; *(int4*)&Bs[buf][sr * 72 + sc + 8] = b1;
    __syncthreads();
    int kn = k0 + 64;
    if (kn < 1024) {
      a0 = *(const int4*)(agp + kn); a1 = *(const int4*)(agp + kn + 8);
      b0 = *(const int4*)(bgp + kn); b1 = *(const int4*)(bgp + kn + 8);
    }
#pragma unroll
    for (int kk = 0; kk < 2; ++kk) {
      short8 a = *(const short8*)&As[buf][(wave * 16 + l15) * 72 + kk * 32 + quad * 8];
#pragma unroll
      for (int c = 0; c < 4; ++c) {
        short8 b = *(const short8*)&Bs[buf][(c * 16 + l15) * 72 + kk * 32 + quad * 8];
        acc[c] = __builtin_amdgcn_mfma_f32_16x16x32_bf16(a, b, acc[c], 0, 0, 0);
      }
    }
  }
  if (blockIdx.x < 16) {
    int s = (n0 >> 2) + l15;
    float kl_sum = 0.f;
#pragma unroll
    for (int r = 0; r < 4; ++r) {
      int b = m0 + wave * 16 + quad * 4 + r;
      size_t row = (size_t)t * NB + b;
      float pm = acc[0][r] + prior_b[s];
      float pl = acc[1][r] + prior_b[256 + s];
      float qm = acc[2][r] + poste[row * 512 + s];
      float ql = acc[3][r] + poste[row * 512 + 256 + s];
      float e = eps[row * 256 + s];
      float z = qm + e * expf(ql);
      xbuf[b * 288 + s] = f2bf(z);
      featc[(size_t)(tt * NB + b) * 1280 + 1024 + s] = f2bf(z);
      if (s < NACT) xbuf[b * 288 + 256 + s] = f2bf(actions[row * NACT + s]);
      float vq = expf(2.f * ql), vp = expf(2.f * pl);
      float dm = qm - pm;
      kl_sum += pl - ql + (vq + dm * dm) / (vp + 1e-8f) - 1.f;
    }
    for (int off = 32; off > 0; off >>= 1) kl_sum += __shfl_down(kl_sum, off);
    if (lane == 0) atomicAdd(acc_kl, 0.5f * kl_sum);
  } else {
    int ng = n0 - 1024;
#pragma unroll
    for (int c = 0; c < 4; ++c)
#pragma unroll
      for (int r = 0; r < 4; ++r) {
        int b = m0 + wave * 16 + quad * 4 + r;
        G[(size_t)b * 3072 + ng + c * 16 + l15] = acc[c][r];
      }
  }
}

// ---------------------------------------------------------------------------
// Phase B kernel 2 (R6, proven): GRU gates + state update. grid (16,8) x 128.
// ---------------------------------------------------------------------------
__global__ __launch_bounds__(128) void gru_step_kernel(
    int t, int tt, const ushort* __restrict__ xbuf, const ushort* __restrict__ wiht,
    const float* __restrict__ G, const float* __restrict__ bih,
    const float* __restrict__ bhh, const unsigned char* __restrict__ dones,
    float* __restrict__ H, ushort* __restrict__ HB, ushort* __restrict__ featc) {
  __shared__ __align__(16) ushort As[2][32 * 40];
  __shared__ __align__(16) ushort Bs[2][3][64 * 40];
  int tid = threadIdx.x;
  int wave = tid >> 6, lane = tid & 63;
  int quad = lane >> 4, l15 = lane & 15;
  int m0 = blockIdx.y * 32, n0 = blockIdx.x * 64;
  int ar = tid >> 2, ac = (tid & 3) * 8;
  int br = tid >> 1, bc = (tid & 1) * 16;
  const ushort* agp = xbuf + (size_t)(m0 + ar) * 288 + ac;
  const ushort* bgp = wiht + (size_t)(n0 + br) * 288 + bc;
  int4 pa = *(const int4*)agp;
  int4 pb[3][2];
#pragma unroll
  for (int gg = 0; gg < 3; ++gg) {
    pb[gg][0] = *(const int4*)(bgp + (size_t)gg * 1024 * 288);
    pb[gg][1] = *(const int4*)(bgp + (size_t)gg * 1024 * 288 + 8);
  }
  f32x4 accv[3][4] = {};
  int buf = 0;
  for (int k0 = 0; k0 < 288; k0 += 32, buf ^= 1) {
    *(int4*)&As[buf][ar * 40 + ac] = pa;
#pragma unroll
    for (int gg = 0; gg < 3; ++gg) {
      *(int4*)&Bs[buf][gg][br * 40 + bc] = pb[gg][0];
      *(int4*)&Bs[buf][gg][br * 40 + bc + 8] = pb[gg][1];
    }
    __syncthreads();
    int kn = k0 + 32;
    if (kn < 288) {
      pa = *(const int4*)(agp + kn);
#pragma unroll
      for (int gg = 0; gg < 3; ++gg) {
        pb[gg][0] = *(const int4*)(bgp + (size_t)gg * 1024 * 288 + kn);
        pb[gg][1] = *(const int4*)(bgp + (size_t)gg * 1024 * 288 + kn + 8);
      }
    }
    short8 a = *(const short8*)&As[buf][(wave * 16 + l15) * 40 + quad * 8];
#pragma unroll
    for (int gg = 0; gg < 3; ++gg) {
#pragma unroll
      for (int c = 0; c < 4; ++c) {
        short8 b = *(const short8*)&Bs[buf][gg][(c * 16 + l15) * 40 + quad * 8];
        accv[gg][c] = __builtin_amdgcn_mfma_f32_16x16x32_bf16(a, b, accv[gg][c], 0, 0, 0);
      }
    }
  }
#pragma unroll
  for (int c = 0; c < 4; ++c) {
#pragma unroll
    for (int r = 0; r < 4; ++r) {
      int b_idx = m0 + wave * 16 + quad * 4 + r;
      int j = n0 + c * 16 + l15;
      const float* g = G + (size_t)b_idx * 3072;
      float ir = accv[0][c][r] + bih[j];
      float iz = accv[1][c][r] + bih[1024 + j];
      float in_ = accv[2][c][r] + bih[2048 + j];
      float hr = g[j] + bhh[j];
      float hz = g[1024 + j] + bhh[1024 + j];
      float hn = g[2048 + j] + bhh[2048 + j];
      float rg = 1.f / (1.f + expf(-(ir + hr)));
      float u = 1.f / (1.f + expf(-(iz + hz)));
      float n = tanhf(in_ + rg * hn);
      float hprev = H[b_idx * 1024 + j];
      float hnext = (1.f - u) * n + u * hprev;
      featc[(size_t)(tt * NB + b_idx) * 1280 + j] = f2bf(hnext);
      float mask = 1.f - (float)dones[t * NB + b_idx];
      float hm = hnext * mask;
      H[b_idx * 1024 + j] = hm;
      HB[b_idx * 1024 + j] = f2bf(hm);
    }
  }
}

// ---------------------------------------------------------------------------
// Decoder-out GEMM + fused recon loss (R6 body).
// ---------------------------------------------------------------------------
__global__ __launch_bounds__(256) void decobs_loss_kernel(
    const ushort* __restrict__ A, const ushort* __restrict__ BT,
    const float* __restrict__ bias, const float* __restrict__ obs_next_g,
    float* __restrict__ acc) {
  __shared__ __align__(16) ushort As[2][64 * 40];
  __shared__ __align__(16) ushort Bs[2][64 * 40];
  int tid = threadIdx.x;
  int wave = tid >> 6, lane = tid & 63;
  int quad = lane >> 4, l15 = lane & 15;
  int m0 = blockIdx.y * 64, n0 = blockIdx.x * 64;
  int sr = tid >> 2, sc = (tid & 3) * 8;
  const ushort* agp = A + (size_t)(m0 + sr) * 2048 + sc;
  const ushort* bgp = BT + (size_t)(n0 + sr) * 1024 + sc;
  int4 pa = *(const int4*)agp;
  int4 pb = *(const int4*)bgp;
  f32x4 accm[4] = {};
  int buf = 0;
  for (int k0 = 0; k0 < 1024; k0 += 32, buf ^= 1) {
    *(int4*)&As[buf][sr * 40 + sc] = pa;
    *(int4*)&Bs[buf][sr * 40 + sc] = pb;
    __syncthreads();
    int kn = k0 + 32;
    if (kn < 1024) {
      pa = *(const int4*)(agp + kn);
      pb = *(const int4*)(bgp + kn);
    }
    short8 a = *(const short8*)&As[buf][(wave * 16 + l15) * 40 + quad * 8];
#pragma unroll
    for (int c = 0; c < 4; ++c) {
      short8 b = *(const short8*)&Bs[buf][(c * 16 + l15) * 40 + quad * 8];
      accm[c] = __builtin_amdgcn_mfma_f32_16x16x32_bf16(a, b, accm[c], 0, 0, 0);
    }
  }
  float local = 0.f;
#pragma unroll
  for (int c = 0; c < 4; ++c) {
#pragma unroll
    for (int r = 0; r < 4; ++r) {
      size_t row = m0 + wave * 16 + quad * 4 + r;
      int col = n0 + c * 16 + l15;
      float v = accm[c][r] + bias[col];
      float d = v - obs_next_g[row * 512 + col];
      local += d * d;
    }
  }
  __shared__ float red[256];
  red[tid] = local;
  __syncthreads();
  for (int st = 128; st > 0; st >>= 1) {
    if (tid < st) red[tid] += red[tid + st];
    __syncthreads();
  }
  if (tid == 0) atomicAdd(&acc[0], red[0]);
}

// Reward matvec + loss. R1 = DR1C + 1024 (bf16, row stride 2048).
__global__ __launch_bounds__(256) void rew_loss_kernel(
    const ushort* __restrict__ R1, const float* __restrict__ w2,
    const float* __restrict__ b2, const float* __restrict__ rewards_g,
    float* __restrict__ acc) {
  int wave = threadIdx.x >> 6;
  int lane = threadIdx.x & 63;
  int row = blockIdx.x * 4 + wave;
  const ushort* rp = R1 + (size_t)row * 2048;
  float s = 0.f;
#pragma unroll
  for (int i = 0; i < 16; ++i) s += bf2f(rp[lane + 64 * i]) * w2[lane + 64 * i];
  for (int off = 32; off > 0; off >>= 1) s += __shfl_down(s, off);
  if (lane == 0) {
    float d = s + b2[0] - rewards_g[row];
    atomicAdd(&acc[1], d * d);
  }
}

__global__ void finalize_kernel(const float* __restrict__ acc, float* __restrict__ out) {
  float recon = acc[0] / ((float)NROWS * 512.f);
  float rew = acc[1] / (float)NROWS;
  float kl = acc[2] / (float)NROWS;
  out[0] = recon + rew + kl;
  out[1] = recon;
  out[2] = rew;
  out[3] = kl;
}

}  // namespace

extern "C" void kernel_launch(void* const* d_in, const int* in_sizes, int n_in,
                              void* d_out, int out_size, void* d_ws, size_t ws_size,
                              hipStream_t stream) {
  const float* obs     = (const float*)d_in[0];
  const float* actions = (const float*)d_in[1];
  const float* rewards = (const float*)d_in[2];
  const unsigned char* dones = (const unsigned char*)d_in[3];
  const float* eps     = (const float*)d_in[4];
  const float* enc_w1  = (const float*)d_in[5];
  const float* enc_b1  = (const float*)d_in[6];
  const float* enc_w2  = (const float*)d_in[7];
  const float* enc_b2  = (const float*)d_in[8];
  const float* gru_wih = (const float*)d_in[9];
  const float* gru_whh = (const float*)d_in[10];
  const float* gru_bih = (const float*)d_in[11];
  const float* gru_bhh = (const float*)d_in[12];
  const float* prior_w = (const float*)d_in[13];
  const float* prior_b = (const float*)d_in[14];
  const float* post_w  = (const float*)d_in[15];
  const float* post_b  = (const float*)d_in[16];
  const float* dec_w1  = (const float*)d_in[17];
  const float* dec_b1  = (const float*)d_in[18];
  const float* dec_w2  = (const float*)d_in[19];
  const float* dec_b2  = (const float*)d_in[20];
  const float* rew_w1  = (const float*)d_in[21];
  const float* rew_b1  = (const float*)d_in[22];
  const float* rew_w2  = (const float*)d_in[23];
  const float* rew_b2  = (const float*)d_in[24];
  float* out = (float*)d_out;
  float* ws = (float*)d_ws;

  float*  POSTE = ws + OFF_POSTE;
  ushort* E1C   = (ushort*)(ws + OFF_E1C);
  ushort* EMBC  = (ushort*)(ws + OFF_EMBC);
  ushort* FEATC = (ushort*)(ws + OFF_FEATC);
  ushort* DR1C  = (ushort*)(ws + OFF_DR1C);
  ushort* WHT   = (ushort*)(ws + OFF_WHT);
  ushort* WIHT  = (ushort*)(ws + OFF_WIHT);
  ushort* WDRT  = (ushort*)(ws + OFF_WDRT);
  ushort* E1T   = (ushort*)(ws + OFF_E1T);
  ushort* E2T   = (ushort*)(ws + OFF_E2T);
  ushort* PET   = (ushort*)(ws + OFF_PET);
  ushort* DW2T  = (ushort*)(ws + OFF_DW2T);
  float*  BDR   = ws + OFF_BDR;
  float*  G     = ws + OFF_G;
  float*  H     = ws + OFF_H;
  ushort* HB    = (ushort*)(ws + OFF_HB);
  float*  ACC   = ws + OFF_ACC;
  ushort* XBUF  = (ushort*)(ws + OFF_XBUF);

  // Phase 0: zero H + HB + ACC (contiguous), build bf16 weights.
  {
    int nzero = NB * 1024 + NB * 512 + 16;  // H + HB + ACC
    zero_kernel<<<(nzero + 255) / 256, 256, 0, stream>>>(H, nzero);
  }
  // WHT: latent rows via tiled permuted transpose (coalesced), whh rows via
  // straight coalesced f2bf.
  build_wht_latent<<<dim3(32, 32), 256, 0, stream>>>(prior_w, post_w, WHT);
  f2bf_kernel<<<(3072 * 1024) / 256, 256, 0, stream>>>(
      gru_whh, WHT + (size_t)1024 * 1024, 3072 * 1024);
  f2bf_kernel<<<(3072 * 288) / 256, 256, 0, stream>>>(gru_wih, WIHT, 3072 * 288);
  trans_conv<<<dim3(1024 / 32, 1280 / 32), 256, 0, stream>>>(dec_w1, WDRT, 1024, 1280);
  trans_conv<<<dim3(1024 / 32, 1280 / 32), 256, 0, stream>>>(rew_w1, WDRT + (size_t)1024 * 1280, 1024, 1280);
  trans_conv<<<dim3(1024 / 32, 512 / 32), 256, 0, stream>>>(enc_w1, E1T, 1024, 512);
  trans_conv<<<dim3(1024 / 32, 1024 / 32), 256, 0, stream>>>(enc_w2, E2T, 1024, 1024);
  trans_conv<<<dim3(512 / 32, 1024 / 32), 256, 0, stream>>>(post_w + (size_t)1024 * 512, PET, 512, 1024);
  trans_conv<<<dim3(512 / 32, 1024 / 32), 256, 0, stream>>>(dec_w2, DW2T, 512, 1024);
  build_bdr<<<8, 256, 0, stream>>>(dec_b1, rew_b1, BDR);

  // Phase A: encoder + posterior-from-emb, chunked per group.
  // obs/enc2 on the 64x128 tile (grid 8x28 = 224 blocks), posterior on 64x64.
  for (int g = 0; g < NGRP; ++g) {
    const float* obs_g = obs + (size_t)g * GROWS * 512;
    gemm_big<64, 1, true><<<dim3(1024 / 128, GROWS / 64), 256, 0, stream>>>(
        (const void*)obs_g, E1T, enc_b1, E1C, 512, 512, 512, 1024);
    gemm_big<64, 1, false><<<dim3(1024 / 128, GROWS / 64), 256, 0, stream>>>(
        (const void*)E1C, E2T, enc_b2, EMBC, 1024, 1024, 1024, 1024);
    gemm_bf16<2, false><<<dim3(8, GROWS / 64), 256, 0, stream>>>(
        (const void*)EMBC, PET, post_b, POSTE + (size_t)g * GROWS * 512, 1024, 1024, 1024, 512);
  }

  // Phase B (R6 structure: per-step kernels) + per-group heads.
  float* acckl = ACC + 2;
  for (int g = 0; g < NGRP; ++g) {
    for (int tt = 0; tt < TGRP; ++tt) {
      int t = g * TGRP + tt;
      step_g_kernel<<<dim3(64, 4), 256, 0, stream>>>(
          t, tt, HB, WHT, prior_b, POSTE, eps, actions, G, XBUF, FEATC, acckl);
      gru_step_kernel<<<dim3(16, 8), 128, 0, stream>>>(
          t, tt, XBUF, WIHT, G, gru_bih, gru_bhh, dones, H, HB, FEATC);
    }
    // featc @ WDRT on the 128x128 tile (grid 16x14 = 224 blocks).
    gemm_big<128, 1, false><<<dim3(2048 / 128, GROWS / 128), 256, 0, stream>>>(
        (const void*)FEATC, WDRT, BDR, DR1C, 1280, 1280, 1280, 2048);
    decobs_loss_kernel<<<dim3(8, GROWS / 64), 256, 0, stream>>>(
        DR1C, DW2T, dec_b2, obs + ((size_t)g * TGRP + 1) * NB * 512, ACC);
    rew_loss_kernel<<<GROWS / 4, 256, 0, stream>>>(
        DR1C + 1024, rew_w2, rew_b2, rewards + (size_t)g * TGRP * NB, ACC);
  }

  finalize_kernel<<<1, 1, 0, stream>>>(ACC, out);
}